// Round 1
// baseline (327.460 us; speedup 1.0000x reference)
//
#include <hip/hip_runtime.h>

typedef __attribute__((ext_vector_type(8))) __bf16 bf16x8;
typedef __attribute__((ext_vector_type(4))) __bf16 bf16x4;
typedef __attribute__((ext_vector_type(4))) float f32x4;

typedef __attribute__((address_space(1))) void as1_void;
typedef __attribute__((address_space(3))) void as3_void;

__device__ __forceinline__ void gl_lds16(const void* g, void* l) {
    __builtin_amdgcn_global_load_lds((const as1_void*)g, (as3_void*)l, 16, 0, 0);
}

// ---------------------------------------------------------------------------
// prep: convert x -> bf16; build WqvT [2048][1024] bf16 (transposed),
// WkN [1024][1024] bf16 (slice convert, rows along k already),
// WpT [1024][1024] bf16 (transposed), bias_qv[2048].
// Sections by blockIdx.x:
//   [0,2048)    WqvT transpose tiles (64 n-tiles x 32 k-tiles)
//   [2048,3072) WpT transpose tiles  (32 x 32)
//   [3072,4096) WkN convert (1024 elems/block)
//   [4096,8192) x convert   (1024 elems/block)
//   [8192]      bias_qv
// ---------------------------------------------------------------------------
__global__ __launch_bounds__(256) void prep_kernel(
    const float* __restrict__ x, const float* __restrict__ caw,
    const float* __restrict__ cab, const float* __restrict__ cpw,
    __bf16* __restrict__ xb, __bf16* __restrict__ wqvt,
    __bf16* __restrict__ wkn, __bf16* __restrict__ wpt,
    float* __restrict__ bqv)
{
    __shared__ float tile[32 * 33];
    int bid = blockIdx.x;
    int tid = threadIdx.x;
    if (bid < 2048) {                      // WqvT[n][k] = caw[k][n<1024?n:n+1024]
        int nt = bid >> 5, kt = bid & 31;
        int tx = tid & 31, ty = tid >> 5;  // 32 x 8
        int n0 = nt * 32, k0 = kt * 32;
        int ncol = (n0 < 1024) ? n0 : (n0 + 1024);
#pragma unroll
        for (int i = 0; i < 4; ++i)
            tile[(ty + i * 8) * 33 + tx] = caw[(long)(k0 + ty + i * 8) * 3072 + ncol + tx];
        __syncthreads();
#pragma unroll
        for (int i = 0; i < 4; ++i)
            wqvt[(long)(n0 + ty + i * 8) * 1024 + k0 + tx] = (__bf16)tile[tx * 33 + ty + i * 8];
    } else if (bid < 3072) {               // WpT[n][k] = cpw[k][n]
        int v = bid - 2048;
        int nt = v >> 5, kt = v & 31;
        int tx = tid & 31, ty = tid >> 5;
        int n0 = nt * 32, k0 = kt * 32;
#pragma unroll
        for (int i = 0; i < 4; ++i)
            tile[(ty + i * 8) * 33 + tx] = cpw[(long)(k0 + ty + i * 8) * 1024 + n0 + tx];
        __syncthreads();
#pragma unroll
        for (int i = 0; i < 4; ++i)
            wpt[(long)(n0 + ty + i * 8) * 1024 + k0 + tx] = (__bf16)tile[tx * 33 + ty + i * 8];
    } else if (bid < 4096) {               // WkN[n][k] = caw[n][1024+k]
        int e = (bid - 3072) * 1024 + tid * 4;
        int n = e >> 10, k = e & 1023;
        float4 f = *(const float4*)(caw + (long)n * 3072 + 1024 + k);
        bf16x4 o = {(__bf16)f.x, (__bf16)f.y, (__bf16)f.z, (__bf16)f.w};
        *(bf16x4*)(wkn + e) = o;
    } else if (bid < 8192) {               // x convert
        long e = (long)(bid - 4096) * 1024 + tid * 4;
        float4 f = *(const float4*)(x + e);
        bf16x4 o = {(__bf16)f.x, (__bf16)f.y, (__bf16)f.z, (__bf16)f.w};
        *(bf16x4*)(xb + e) = o;
    } else {                               // bias_qv
        for (int i = tid; i < 2048; i += 256)
            bqv[i] = cab[i < 1024 ? i : i + 1024];
    }
}

// ---------------------------------------------------------------------------
// Generic GEMM: C[M,N] = A[M,K](bf16,row-major) x BT[N,K](bf16,row-major) + bias
// 128x128 tile, BK=32, 4 waves each 64x64 (4x4 of 16x16x32 MFMA).
// global_load_lds width-16 staging, linear LDS (no pad).
// ---------------------------------------------------------------------------
template <bool BF16OUT>
__global__ __launch_bounds__(256) void gemm_bt(
    const __bf16* __restrict__ A, int lda,
    const __bf16* __restrict__ B, int ldb,
    const float* __restrict__ bias,
    void* __restrict__ C, int ldc, int K)
{
    __shared__ __bf16 As[128 * 32];
    __shared__ __bf16 Bs[128 * 32];
    const int tid = threadIdx.x;
    const int lane = tid & 63;
    const int wave = tid >> 6;
    const int quad = lane >> 4, l16 = lane & 15;
    const long m0 = (long)blockIdx.y * 128;
    const long n0 = (long)blockIdx.x * 128;
    const int wm = (wave >> 1) * 64, wn = (wave & 1) * 64;
    const int s0 = tid, s1 = tid + 256;

    f32x4 acc[4][4] = {};

    for (int k0 = 0; k0 < K; k0 += 32) {
        gl_lds16(A + (m0 + (s0 >> 2)) * lda + k0 + (s0 & 3) * 8, As + s0 * 8);
        gl_lds16(A + (m0 + (s1 >> 2)) * lda + k0 + (s1 & 3) * 8, As + s1 * 8);
        gl_lds16(B + (n0 + (s0 >> 2)) * ldb + k0 + (s0 & 3) * 8, Bs + s0 * 8);
        gl_lds16(B + (n0 + (s1 >> 2)) * ldb + k0 + (s1 & 3) * 8, Bs + s1 * 8);
        __syncthreads();
        bf16x8 af[4], bfr[4];
#pragma unroll
        for (int i = 0; i < 4; ++i)
            af[i] = *(const bf16x8*)(As + (wm + i * 16 + l16) * 32 + quad * 8);
#pragma unroll
        for (int j = 0; j < 4; ++j)
            bfr[j] = *(const bf16x8*)(Bs + (wn + j * 16 + l16) * 32 + quad * 8);
#pragma unroll
        for (int i = 0; i < 4; ++i)
#pragma unroll
            for (int j = 0; j < 4; ++j)
                acc[i][j] = __builtin_amdgcn_mfma_f32_16x16x32_bf16(af[i], bfr[j], acc[i][j], 0, 0, 0);
        __syncthreads();
    }
#pragma unroll
    for (int i = 0; i < 4; ++i) {
        long row = m0 + wm + i * 16 + quad * 4;
#pragma unroll
        for (int j = 0; j < 4; ++j) {
            int col = (int)n0 + wn + j * 16 + l16;
            float bb = bias[col];
#pragma unroll
            for (int r = 0; r < 4; ++r) {
                float v = acc[i][j][r] + bb;
                if (BF16OUT)
                    ((__bf16*)C)[(row + r) * ldc + col] = (__bf16)v;
                else
                    ((float*)C)[(row + r) * ldc + col] = v;
            }
        }
    }
}

// ---------------------------------------------------------------------------
// transpose V slice of tqv into VT[bh][d][s]  (bf16), per (bh, 64-row s-tile)
// ---------------------------------------------------------------------------
__global__ __launch_bounds__(256) void transpose_v(
    const __bf16* __restrict__ TQV, __bf16* __restrict__ VT)
{
    __shared__ unsigned short tile[64 * 65];
    int bid = blockIdx.x;          // 1024 blocks
    int bh = bid >> 5, st = bid & 31;
    int b = bh >> 4, h = bh & 15;
    long srow = (long)b * 2048 + st * 64;
#pragma unroll
    for (int p = 0; p < 16; ++p) {
        int idx = p * 256 + threadIdx.x;
        int sl = idx >> 6, d = idx & 63;
        tile[sl * 65 + d] = ((const unsigned short*)TQV)[(srow + sl) * 2048 + 1024 + h * 64 + d];
    }
    __syncthreads();
#pragma unroll
    for (int p = 0; p < 16; ++p) {
        int idx = p * 256 + threadIdx.x;
        int d = idx >> 6, sl = idx & 63;
        ((unsigned short*)VT)[((long)bh * 64 + d) * 2048 + st * 64 + sl] = tile[sl * 65 + d];
    }
}

// ---------------------------------------------------------------------------
// Flash attention: grid (qt=S/64, bh=B*H). Block 256 = 4 waves, wave owns a
// 16-q-row strip. K source = raw x (bf16), V via VT. Online softmax.
// ---------------------------------------------------------------------------
__global__ __launch_bounds__(256) void attn_kernel(
    const __bf16* __restrict__ Q,   // [4096][1024]
    const __bf16* __restrict__ Xb,  // [4096][1024]
    const __bf16* __restrict__ VT,  // [32*64][2048]
    __bf16* __restrict__ O)         // [4096][1024]
{
    __shared__ __bf16 Qs[64 * 64];
    __shared__ __bf16 Ks[64 * 64];
    __shared__ __bf16 Vs[64 * 64];
    __shared__ __bf16 Ps[4 * 16 * 64];
    const int tid = threadIdx.x;
    const int lane = tid & 63;
    const int wave = tid >> 6;
    const int quad = lane >> 4, l16 = lane & 15;
    const int qt = blockIdx.x;
    const int bh = blockIdx.y;
    const int b = bh >> 4, h = bh & 15;
    const long rowbase = (long)b * 2048;
    const int q0 = qt * 64;

    {
        int s = tid;
        gl_lds16(Q + (rowbase + q0 + (s >> 3)) * 1024 + h * 64 + (s & 7) * 8, Qs + s * 8);
        s = tid + 256;
        gl_lds16(Q + (rowbase + q0 + (s >> 3)) * 1024 + h * 64 + (s & 7) * 8, Qs + s * 8);
    }

    f32x4 oacc[4] = {};
    float m_run[4], l_run[4];
#pragma unroll
    for (int r = 0; r < 4; ++r) { m_run[r] = -1e30f; l_run[r] = 0.f; }

    for (int j = 0; j <= qt; ++j) {
        int s = tid;
        gl_lds16(Xb + (rowbase + j * 64 + (s >> 3)) * 1024 + h * 64 + (s & 7) * 8, Ks + s * 8);
        gl_lds16(VT + ((long)bh * 64 + (s >> 3)) * 2048 + j * 64 + (s & 7) * 8, Vs + s * 8);
        s = tid + 256;
        gl_lds16(Xb + (rowbase + j * 64 + (s >> 3)) * 1024 + h * 64 + (s & 7) * 8, Ks + s * 8);
        gl_lds16(VT + ((long)bh * 64 + (s >> 3)) * 2048 + j * 64 + (s & 7) * 8, Vs + s * 8);
        __syncthreads();

        // S = Q K^T (per-wave 16x64 strip)
        f32x4 sacc[4] = {};
#pragma unroll
        for (int kk = 0; kk < 2; ++kk) {
            bf16x8 aq = *(const bf16x8*)(Qs + (wave * 16 + l16) * 64 + kk * 32 + quad * 8);
#pragma unroll
            for (int jt = 0; jt < 4; ++jt) {
                bf16x8 bk = *(const bf16x8*)(Ks + (jt * 16 + l16) * 64 + kk * 32 + quad * 8);
                sacc[jt] = __builtin_amdgcn_mfma_f32_16x16x32_bf16(aq, bk, sacc[jt], 0, 0, 0);
            }
        }

        // online softmax
        float pv[4][4];
        int qg_base = q0 + wave * 16 + quad * 4;
        int kv_base = j * 64 + l16;
#pragma unroll
        for (int r = 0; r < 4; ++r) {
            int qg = qg_base + r;
            float sv[4];
            float mx = -1e30f;
#pragma unroll
            for (int jt = 0; jt < 4; ++jt) {
                float sval = sacc[jt][r] * 0.125f;
                if (kv_base + jt * 16 > qg) sval = -1e30f;
                sv[jt] = sval;
                mx = fmaxf(mx, sval);
            }
#pragma unroll
            for (int off = 1; off < 16; off <<= 1)
                mx = fmaxf(mx, __shfl_xor(mx, off));
            float mnew = fmaxf(m_run[r], mx);
            float alpha = __expf(m_run[r] - mnew);
            float psum = 0.f;
#pragma unroll
            for (int jt = 0; jt < 4; ++jt) {
                float p = __expf(sv[jt] - mnew);
                pv[r][jt] = p;
                psum += p;
            }
#pragma unroll
            for (int off = 1; off < 16; off <<= 1)
                psum += __shfl_xor(psum, off);
            l_run[r] = l_run[r] * alpha + psum;
            m_run[r] = mnew;
#pragma unroll
            for (int jt = 0; jt < 4; ++jt) oacc[jt][r] *= alpha;
        }

        // P -> LDS (per-wave region; no barrier needed)
        __bf16* Pw = Ps + wave * 16 * 64;
#pragma unroll
        for (int r = 0; r < 4; ++r)
#pragma unroll
            for (int jt = 0; jt < 4; ++jt)
                Pw[(quad * 4 + r) * 64 + jt * 16 + l16] = (__bf16)pv[r][jt];

        // O += P V
#pragma unroll
        for (int kk = 0; kk < 2; ++kk) {
            bf16x8 pa = *(const bf16x8*)(Pw + l16 * 64 + kk * 32 + quad * 8);
#pragma unroll
            for (int jt = 0; jt < 4; ++jt) {
                bf16x8 vb = *(const bf16x8*)(Vs + (jt * 16 + l16) * 64 + kk * 32 + quad * 8);
                oacc[jt] = __builtin_amdgcn_mfma_f32_16x16x32_bf16(pa, vb, oacc[jt], 0, 0, 0);
            }
        }
        __syncthreads();
    }

#pragma unroll
    for (int jt = 0; jt < 4; ++jt) {
#pragma unroll
        for (int r = 0; r < 4; ++r) {
            float v = oacc[jt][r] / l_run[r];
            long row = rowbase + q0 + wave * 16 + quad * 4 + r;
            O[row * 1024 + h * 64 + jt * 16 + l16] = (__bf16)v;
        }
    }
}

// ---------------------------------------------------------------------------
extern "C" void kernel_launch(void* const* d_in, const int* in_sizes, int n_in,
                              void* d_out, int out_size, void* d_ws, size_t ws_size,
                              hipStream_t stream) {
    const float* x   = (const float*)d_in[0];
    const float* caw = (const float*)d_in[1];
    const float* cab = (const float*)d_in[2];
    const float* cpw = (const float*)d_in[3];
    const float* cpb = (const float*)d_in[4];

    char* p = (char*)d_ws;
    auto alloc = [&](size_t bytes) {
        void* r = (void*)p;
        p += (bytes + 255) & ~(size_t)255;
        return r;
    };
    __bf16* xb   = (__bf16*)alloc(4096UL * 1024 * 2);   // x bf16
    __bf16* wqvt = (__bf16*)alloc(2048UL * 1024 * 2);   // [Wq;Wv]^T
    __bf16* wkn  = (__bf16*)alloc(1024UL * 1024 * 2);   // Wk rows
    __bf16* wpt  = (__bf16*)alloc(1024UL * 1024 * 2);   // Wp^T
    float*  bqv  = (float*) alloc(2048UL * 4);          // [qb;vb]
    __bf16* tqv  = (__bf16*)alloc(4096UL * 2048 * 2);   // [t | v]
    __bf16* qbuf = (__bf16*)alloc(4096UL * 1024 * 2);   // q
    __bf16* vt   = (__bf16*)alloc(2048UL * 2048 * 2);   // V^T per (b,h)
    __bf16* attn = (__bf16*)alloc(4096UL * 1024 * 2);   // attention out

    prep_kernel<<<8193, 256, 0, stream>>>(x, caw, cab, cpw, xb, wqvt, wkn, wpt, bqv);

    // tqv = x @ [Wq|Wv] + [qb|vb]
    gemm_bt<true><<<dim3(16, 32), 256, 0, stream>>>(xb, 1024, wqvt, 1024, bqv,
                                                    (void*)tqv, 2048, 1024);
    // VT from v half of tqv
    transpose_v<<<1024, 256, 0, stream>>>(tqv, vt);
    // q = t @ Wk^T + kb   (t = cols [0,1024) of tqv)
    gemm_bt<true><<<dim3(8, 32), 256, 0, stream>>>(tqv, 2048, wkn, 1024, cab + 1024,
                                                   (void*)qbuf, 1024, 1024);
    // attention
    attn_kernel<<<dim3(32, 32), 256, 0, stream>>>(qbuf, xb, vt, attn);
    // out = attn @ Wp + pb (fp32)
    gemm_bt<false><<<dim3(8, 32), 256, 0, stream>>>(attn, 1024, wpt, 1024, cpb,
                                                    d_out, 1024, 1024);
    (void)in_sizes; (void)n_in; (void)out_size; (void)ws_size;
}

// Round 2
// 245.486 us; speedup vs baseline: 1.3339x; 1.3339x over previous
//
#include <hip/hip_runtime.h>

typedef __attribute__((ext_vector_type(8))) __bf16 bf16x8;
typedef __attribute__((ext_vector_type(4))) __bf16 bf16x4;
typedef __attribute__((ext_vector_type(4))) float f32x4;

typedef __attribute__((address_space(1))) void as1_void;
typedef __attribute__((address_space(3))) void as3_void;

__device__ __forceinline__ void gl_lds16(const void* g, void* l) {
    __builtin_amdgcn_global_load_lds((const as1_void*)g, (as3_void*)l, 16, 0, 0);
}

// swizzled fragment pointer for a [rows][64] bf16 LDS buffer (row = 128 B,
// 16-byte chunks XOR-swizzled by row&7 to kill bank conflicts)
__device__ __forceinline__ const bf16x8* swz(const __bf16* base, int row, int chunk) {
    return (const bf16x8*)((const char*)base + row * 128 + ((chunk ^ (row & 7)) * 16));
}

// ---------------------------------------------------------------------------
// prep: convert x -> bf16; build WqvT [2048][1024] bf16 (transposed),
// WkN [1024][1024], WpT [1024][1024], bias_qv[2048].
// ---------------------------------------------------------------------------
__global__ __launch_bounds__(256) void prep_kernel(
    const float* __restrict__ x, const float* __restrict__ caw,
    const float* __restrict__ cab, const float* __restrict__ cpw,
    __bf16* __restrict__ xb, __bf16* __restrict__ wqvt,
    __bf16* __restrict__ wkn, __bf16* __restrict__ wpt,
    float* __restrict__ bqv)
{
    __shared__ float tile[32 * 33];
    int bid = blockIdx.x;
    int tid = threadIdx.x;
    if (bid < 2048) {                      // WqvT[n][k] = caw[k][n<1024?n:n+1024]
        int nt = bid >> 5, kt = bid & 31;
        int tx = tid & 31, ty = tid >> 5;  // 32 x 8
        int n0 = nt * 32, k0 = kt * 32;
        int ncol = (n0 < 1024) ? n0 : (n0 + 1024);
#pragma unroll
        for (int i = 0; i < 4; ++i)
            tile[(ty + i * 8) * 33 + tx] = caw[(long)(k0 + ty + i * 8) * 3072 + ncol + tx];
        __syncthreads();
#pragma unroll
        for (int i = 0; i < 4; ++i)
            wqvt[(long)(n0 + ty + i * 8) * 1024 + k0 + tx] = (__bf16)tile[tx * 33 + ty + i * 8];
    } else if (bid < 3072) {               // WpT[n][k] = cpw[k][n]
        int v = bid - 2048;
        int nt = v >> 5, kt = v & 31;
        int tx = tid & 31, ty = tid >> 5;
        int n0 = nt * 32, k0 = kt * 32;
#pragma unroll
        for (int i = 0; i < 4; ++i)
            tile[(ty + i * 8) * 33 + tx] = cpw[(long)(k0 + ty + i * 8) * 1024 + n0 + tx];
        __syncthreads();
#pragma unroll
        for (int i = 0; i < 4; ++i)
            wpt[(long)(n0 + ty + i * 8) * 1024 + k0 + tx] = (__bf16)tile[tx * 33 + ty + i * 8];
    } else if (bid < 4096) {               // WkN[n][k] = caw[n][1024+k]
        int e = (bid - 3072) * 1024 + tid * 4;
        int n = e >> 10, k = e & 1023;
        float4 f = *(const float4*)(caw + (long)n * 3072 + 1024 + k);
        bf16x4 o = {(__bf16)f.x, (__bf16)f.y, (__bf16)f.z, (__bf16)f.w};
        *(bf16x4*)(wkn + e) = o;
    } else if (bid < 8192) {               // x convert
        long e = (long)(bid - 4096) * 1024 + tid * 4;
        float4 f = *(const float4*)(x + e);
        bf16x4 o = {(__bf16)f.x, (__bf16)f.y, (__bf16)f.z, (__bf16)f.w};
        *(bf16x4*)(xb + e) = o;
    } else {                               // bias_qv
        for (int i = tid; i < 2048; i += 256)
            bqv[i] = cab[i < 1024 ? i : i + 1024];
    }
}

// ---------------------------------------------------------------------------
// Generic GEMM: C[M,N] = A[M,K](bf16 rm) x BT[N,K](bf16 rm) + bias
// ---------------------------------------------------------------------------
template <bool BF16OUT>
__global__ __launch_bounds__(256) void gemm_bt(
    const __bf16* __restrict__ A, int lda,
    const __bf16* __restrict__ B, int ldb,
    const float* __restrict__ bias,
    void* __restrict__ C, int ldc, int K)
{
    __shared__ __bf16 As[128 * 32];
    __shared__ __bf16 Bs[128 * 32];
    const int tid = threadIdx.x;
    const int lane = tid & 63;
    const int wave = tid >> 6;
    const int quad = lane >> 4, l16 = lane & 15;
    const long m0 = (long)blockIdx.y * 128;
    const long n0 = (long)blockIdx.x * 128;
    const int wm = (wave >> 1) * 64, wn = (wave & 1) * 64;
    const int s0 = tid, s1 = tid + 256;

    f32x4 acc[4][4] = {};

    for (int k0 = 0; k0 < K; k0 += 32) {
        gl_lds16(A + (m0 + (s0 >> 2)) * lda + k0 + (s0 & 3) * 8, As + s0 * 8);
        gl_lds16(A + (m0 + (s1 >> 2)) * lda + k0 + (s1 & 3) * 8, As + s1 * 8);
        gl_lds16(B + (n0 + (s0 >> 2)) * ldb + k0 + (s0 & 3) * 8, Bs + s0 * 8);
        gl_lds16(B + (n0 + (s1 >> 2)) * ldb + k0 + (s1 & 3) * 8, Bs + s1 * 8);
        __syncthreads();
        bf16x8 af[4], bfr[4];
#pragma unroll
        for (int i = 0; i < 4; ++i)
            af[i] = *(const bf16x8*)(As + (wm + i * 16 + l16) * 32 + quad * 8);
#pragma unroll
        for (int j = 0; j < 4; ++j)
            bfr[j] = *(const bf16x8*)(Bs + (wn + j * 16 + l16) * 32 + quad * 8);
#pragma unroll
        for (int i = 0; i < 4; ++i)
#pragma unroll
            for (int j = 0; j < 4; ++j)
                acc[i][j] = __builtin_amdgcn_mfma_f32_16x16x32_bf16(af[i], bfr[j], acc[i][j], 0, 0, 0);
        __syncthreads();
    }
#pragma unroll
    for (int i = 0; i < 4; ++i) {
        long row = m0 + wm + i * 16 + quad * 4;
#pragma unroll
        for (int j = 0; j < 4; ++j) {
            int col = (int)n0 + wn + j * 16 + l16;
            float bb = bias[col];
#pragma unroll
            for (int r = 0; r < 4; ++r) {
                float v = acc[i][j][r] + bb;
                if (BF16OUT)
                    ((__bf16*)C)[(row + r) * ldc + col] = (__bf16)v;
                else
                    ((float*)C)[(row + r) * ldc + col] = v;
            }
        }
    }
}

// ---------------------------------------------------------------------------
// transpose V slice of tqv into VT[bh][d][s]
// ---------------------------------------------------------------------------
__global__ __launch_bounds__(256) void transpose_v(
    const __bf16* __restrict__ TQV, __bf16* __restrict__ VT)
{
    __shared__ unsigned short tile[64 * 65];
    int bid = blockIdx.x;          // 1024 blocks
    int bh = bid >> 5, st = bid & 31;
    int b = bh >> 4, h = bh & 15;
    long srow = (long)b * 2048 + st * 64;
#pragma unroll
    for (int p = 0; p < 16; ++p) {
        int idx = p * 256 + threadIdx.x;
        int sl = idx >> 6, d = idx & 63;
        tile[sl * 65 + d] = ((const unsigned short*)TQV)[(srow + sl) * 2048 + 1024 + h * 64 + d];
    }
    __syncthreads();
#pragma unroll
    for (int p = 0; p < 16; ++p) {
        int idx = p * 256 + threadIdx.x;
        int d = idx >> 6, sl = idx & 63;
        ((unsigned short*)VT)[((long)bh * 64 + d) * 2048 + st * 64 + sl] = tile[sl * 65 + d];
    }
}

// ---------------------------------------------------------------------------
// Flash attention, causal-balanced: grid (pair=16, bh=32). Block handles
// q-tiles {qa=pair, qb=31-pair} -> every block does exactly 33 tile-units.
// K/V staged once per kv tile, shared by both q-tiles. All LDS buffers
// XOR-chunk-swizzled. Row-sums (l) accumulated via MFMA against ones.
// ---------------------------------------------------------------------------
__global__ __launch_bounds__(256) void attn_kernel(
    const __bf16* __restrict__ Q,   // [4096][1024]
    const __bf16* __restrict__ Xb,  // [4096][1024]
    const __bf16* __restrict__ VT,  // [32*64][2048]
    __bf16* __restrict__ O)         // [4096][1024]
{
    __shared__ __bf16 Qs[2 * 64 * 64];
    __shared__ __bf16 Ks[64 * 64];
    __shared__ __bf16 Vs[64 * 64];
    __shared__ __bf16 Ps[4 * 16 * 64];
    const int tid = threadIdx.x;
    const int lane = tid & 63;
    const int wave = tid >> 6;
    const int quad = lane >> 4, l16 = lane & 15;
    const int qa = blockIdx.x;        // 0..15
    const int qb = 31 - qa;           // 16..31
    const int bh = blockIdx.y;
    const int b = bh >> 4, h = bh & 15;
    const long rowbase = (long)b * 2048;

    bf16x8 ones;
#pragma unroll
    for (int i = 0; i < 8; ++i) ones[i] = (__bf16)1.0f;

    // stage both Q tiles (swizzled source columns, linear LDS slots)
    {
        int s0 = tid, s1 = tid + 256;
        int c0 = ((s0 & 7) ^ ((s0 >> 3) & 7)) * 8;
        int c1 = ((s1 & 7) ^ ((s1 >> 3) & 7)) * 8;
        gl_lds16(Q + (rowbase + qa * 64 + (s0 >> 3)) * 1024 + h * 64 + c0, Qs + s0 * 8);
        gl_lds16(Q + (rowbase + qa * 64 + (s1 >> 3)) * 1024 + h * 64 + c1, Qs + s1 * 8);
        gl_lds16(Q + (rowbase + qb * 64 + (s0 >> 3)) * 1024 + h * 64 + c0, Qs + 4096 + s0 * 8);
        gl_lds16(Q + (rowbase + qb * 64 + (s1 >> 3)) * 1024 + h * 64 + c1, Qs + 4096 + s1 * 8);
    }

    f32x4 oacc[2][4] = {};
    f32x4 lacc[2] = {};
    float m_run[2][4];
#pragma unroll
    for (int t = 0; t < 2; ++t)
#pragma unroll
        for (int r = 0; r < 4; ++r) m_run[t][r] = -1e30f;

    for (int j = 0; j <= qb; ++j) {
        {
            int s0 = tid, s1 = tid + 256;
            int c0 = ((s0 & 7) ^ ((s0 >> 3) & 7)) * 8;
            int c1 = ((s1 & 7) ^ ((s1 >> 3) & 7)) * 8;
            gl_lds16(Xb + (rowbase + j * 64 + (s0 >> 3)) * 1024 + h * 64 + c0, Ks + s0 * 8);
            gl_lds16(Xb + (rowbase + j * 64 + (s1 >> 3)) * 1024 + h * 64 + c1, Ks + s1 * 8);
            gl_lds16(VT + ((long)bh * 64 + (s0 >> 3)) * 2048 + j * 64 + c0, Vs + s0 * 8);
            gl_lds16(VT + ((long)bh * 64 + (s1 >> 3)) * 2048 + j * 64 + c1, Vs + s1 * 8);
        }
        __syncthreads();

#pragma unroll
        for (int t = 0; t < 2; ++t) {
            if (t == 0 && j > qa) continue;
            const int qt = t ? qb : qa;
            const __bf16* Qt = Qs + t * 4096;
            __bf16* Pw = Ps + wave * 1024;

            // S = Q K^T (16x64 strip per wave)
            f32x4 sacc[4] = {};
#pragma unroll
            for (int kk = 0; kk < 2; ++kk) {
                bf16x8 aq = *swz(Qt, wave * 16 + l16, kk * 4 + quad);
#pragma unroll
                for (int jt = 0; jt < 4; ++jt)
                    sacc[jt] = __builtin_amdgcn_mfma_f32_16x16x32_bf16(
                        aq, *swz(Ks, jt * 16 + l16, kk * 4 + quad), sacc[jt], 0, 0, 0);
            }

            const bool diag = (j == qt);
#pragma unroll
            for (int r = 0; r < 4; ++r) {
                float sv[4];
#pragma unroll
                for (int jt = 0; jt < 4; ++jt) sv[jt] = sacc[jt][r] * 0.125f;
                if (diag) {
                    int qg = qt * 64 + wave * 16 + quad * 4 + r;
                    int kvb = j * 64 + l16;
#pragma unroll
                    for (int jt = 0; jt < 4; ++jt)
                        if (kvb + jt * 16 > qg) sv[jt] = -1e30f;
                }
                float mloc = fmaxf(fmaxf(sv[0], sv[1]), fmaxf(sv[2], sv[3]));
#pragma unroll
                for (int off = 1; off < 16; off <<= 1)
                    mloc = fmaxf(mloc, __shfl_xor(mloc, off));
                float mnew = fmaxf(m_run[t][r], mloc);
                float alpha = __expf(m_run[t][r] - mnew);
                m_run[t][r] = mnew;
                lacc[t][r] *= alpha;
#pragma unroll
                for (int jt = 0; jt < 4; ++jt) {
                    float p = __expf(sv[jt] - mnew);
                    oacc[t][jt][r] *= alpha;
                    int col = jt * 16 + l16;
                    int prow = quad * 4 + r;
                    *(__bf16*)((char*)Pw + prow * 128 + (((col >> 3) ^ (prow & 7)) * 16)
                               + (col & 7) * 2) = (__bf16)p;
                }
            }

            // O += P V ; l += P * ones  (per-wave P buffer, no barrier needed)
#pragma unroll
            for (int kk = 0; kk < 2; ++kk) {
                bf16x8 pa = *swz(Pw, l16, kk * 4 + quad);
                lacc[t] = __builtin_amdgcn_mfma_f32_16x16x32_bf16(pa, ones, lacc[t], 0, 0, 0);
#pragma unroll
                for (int jt = 0; jt < 4; ++jt)
                    oacc[t][jt] = __builtin_amdgcn_mfma_f32_16x16x32_bf16(
                        pa, *swz(Vs, jt * 16 + l16, kk * 4 + quad), oacc[t][jt], 0, 0, 0);
            }
        }
        __syncthreads();
    }

#pragma unroll
    for (int t = 0; t < 2; ++t) {
        const int qt = t ? qb : qa;
        float inv[4];
#pragma unroll
        for (int r = 0; r < 4; ++r) inv[r] = 1.0f / lacc[t][r];
#pragma unroll
        for (int jt = 0; jt < 4; ++jt)
#pragma unroll
            for (int r = 0; r < 4; ++r) {
                long row = rowbase + qt * 64 + wave * 16 + quad * 4 + r;
                O[row * 1024 + h * 64 + jt * 16 + l16] = (__bf16)(oacc[t][jt][r] * inv[r]);
            }
    }
}

// ---------------------------------------------------------------------------
extern "C" void kernel_launch(void* const* d_in, const int* in_sizes, int n_in,
                              void* d_out, int out_size, void* d_ws, size_t ws_size,
                              hipStream_t stream) {
    const float* x   = (const float*)d_in[0];
    const float* caw = (const float*)d_in[1];
    const float* cab = (const float*)d_in[2];
    const float* cpw = (const float*)d_in[3];
    const float* cpb = (const float*)d_in[4];

    char* p = (char*)d_ws;
    auto alloc = [&](size_t bytes) {
        void* r = (void*)p;
        p += (bytes + 255) & ~(size_t)255;
        return r;
    };
    __bf16* xb   = (__bf16*)alloc(4096UL * 1024 * 2);   // x bf16
    __bf16* wqvt = (__bf16*)alloc(2048UL * 1024 * 2);   // [Wq;Wv]^T
    __bf16* wkn  = (__bf16*)alloc(1024UL * 1024 * 2);   // Wk rows
    __bf16* wpt  = (__bf16*)alloc(1024UL * 1024 * 2);   // Wp^T
    float*  bqv  = (float*) alloc(2048UL * 4);          // [qb;vb]
    __bf16* tqv  = (__bf16*)alloc(4096UL * 2048 * 2);   // [t | v]
    __bf16* qbuf = (__bf16*)alloc(4096UL * 1024 * 2);   // q
    __bf16* vt   = (__bf16*)alloc(2048UL * 2048 * 2);   // V^T per (b,h)
    __bf16* attn = (__bf16*)alloc(4096UL * 1024 * 2);   // attention out

    prep_kernel<<<8193, 256, 0, stream>>>(x, caw, cab, cpw, xb, wqvt, wkn, wpt, bqv);

    // tqv = x @ [Wq|Wv] + [qb|vb]
    gemm_bt<true><<<dim3(16, 32), 256, 0, stream>>>(xb, 1024, wqvt, 1024, bqv,
                                                    (void*)tqv, 2048, 1024);
    // VT from v half of tqv
    transpose_v<<<1024, 256, 0, stream>>>(tqv, vt);
    // q = t @ Wk^T + kb   (t = cols [0,1024) of tqv)
    gemm_bt<true><<<dim3(8, 32), 256, 0, stream>>>(tqv, 2048, wkn, 1024, cab + 1024,
                                                   (void*)qbuf, 1024, 1024);
    // attention (paired causal tiles)
    attn_kernel<<<dim3(16, 32), 256, 0, stream>>>(qbuf, xb, vt, attn);
    // out = attn @ Wp + pb (fp32)
    gemm_bt<false><<<dim3(8, 32), 256, 0, stream>>>(attn, 1024, wpt, 1024, cpb,
                                                    d_out, 1024, 1024);
    (void)in_sizes; (void)n_in; (void)out_size; (void)ws_size;
}

// Round 3
// 226.024 us; speedup vs baseline: 1.4488x; 1.0861x over previous
//
#include <hip/hip_runtime.h>

typedef __attribute__((ext_vector_type(8))) __bf16 bf16x8;
typedef __attribute__((ext_vector_type(4))) __bf16 bf16x4;
typedef __attribute__((ext_vector_type(4))) float f32x4;

typedef __attribute__((address_space(1))) void as1_void;
typedef __attribute__((address_space(3))) void as3_void;

__device__ __forceinline__ void gl_lds16(const void* g, void* l) {
    __builtin_amdgcn_global_load_lds((const as1_void*)g, (as3_void*)l, 16, 0, 0);
}

// swizzled fragment pointer for a [rows][64] bf16 LDS buffer (row = 128 B,
// 16-byte chunks XOR-swizzled by row&7 to kill bank conflicts)
__device__ __forceinline__ const bf16x8* swz(const __bf16* base, int row, int chunk) {
    return (const bf16x8*)((const char*)base + row * 128 + ((chunk ^ (row & 7)) * 16));
}

// ---------------------------------------------------------------------------
// prep: convert x -> bf16; build WqvT [2048][1024] bf16 (transposed),
// WkN [1024][1024], WpT [1024][1024], bias_qv[2048].
// ---------------------------------------------------------------------------
__global__ __launch_bounds__(256) void prep_kernel(
    const float* __restrict__ x, const float* __restrict__ caw,
    const float* __restrict__ cab, const float* __restrict__ cpw,
    __bf16* __restrict__ xb, __bf16* __restrict__ wqvt,
    __bf16* __restrict__ wkn, __bf16* __restrict__ wpt,
    float* __restrict__ bqv)
{
    __shared__ float tile[32 * 33];
    int bid = blockIdx.x;
    int tid = threadIdx.x;
    if (bid < 2048) {                      // WqvT[n][k] = caw[k][n<1024?n:n+1024]
        int nt = bid >> 5, kt = bid & 31;
        int tx = tid & 31, ty = tid >> 5;  // 32 x 8
        int n0 = nt * 32, k0 = kt * 32;
        int ncol = (n0 < 1024) ? n0 : (n0 + 1024);
#pragma unroll
        for (int i = 0; i < 4; ++i)
            tile[(ty + i * 8) * 33 + tx] = caw[(long)(k0 + ty + i * 8) * 3072 + ncol + tx];
        __syncthreads();
#pragma unroll
        for (int i = 0; i < 4; ++i)
            wqvt[(long)(n0 + ty + i * 8) * 1024 + k0 + tx] = (__bf16)tile[tx * 33 + ty + i * 8];
    } else if (bid < 3072) {               // WpT[n][k] = cpw[k][n]
        int v = bid - 2048;
        int nt = v >> 5, kt = v & 31;
        int tx = tid & 31, ty = tid >> 5;
        int n0 = nt * 32, k0 = kt * 32;
#pragma unroll
        for (int i = 0; i < 4; ++i)
            tile[(ty + i * 8) * 33 + tx] = cpw[(long)(k0 + ty + i * 8) * 1024 + n0 + tx];
        __syncthreads();
#pragma unroll
        for (int i = 0; i < 4; ++i)
            wpt[(long)(n0 + ty + i * 8) * 1024 + k0 + tx] = (__bf16)tile[tx * 33 + ty + i * 8];
    } else if (bid < 4096) {               // WkN[n][k] = caw[n][1024+k]
        int e = (bid - 3072) * 1024 + tid * 4;
        int n = e >> 10, k = e & 1023;
        float4 f = *(const float4*)(caw + (long)n * 3072 + 1024 + k);
        bf16x4 o = {(__bf16)f.x, (__bf16)f.y, (__bf16)f.z, (__bf16)f.w};
        *(bf16x4*)(wkn + e) = o;
    } else if (bid < 8192) {               // x convert
        long e = (long)(bid - 4096) * 1024 + tid * 4;
        float4 f = *(const float4*)(x + e);
        bf16x4 o = {(__bf16)f.x, (__bf16)f.y, (__bf16)f.z, (__bf16)f.w};
        *(bf16x4*)(xb + e) = o;
    } else {                               // bias_qv
        for (int i = tid; i < 2048; i += 256)
            bqv[i] = cab[i < 1024 ? i : i + 1024];
    }
}

// ---------------------------------------------------------------------------
// Generic GEMM: C[M,N] = A[M,K](bf16 rm) x BT[N,K](bf16 rm) + bias
// ---------------------------------------------------------------------------
template <bool BF16OUT>
__global__ __launch_bounds__(256) void gemm_bt(
    const __bf16* __restrict__ A, int lda,
    const __bf16* __restrict__ B, int ldb,
    const float* __restrict__ bias,
    void* __restrict__ C, int ldc, int K)
{
    __shared__ __bf16 As[128 * 32];
    __shared__ __bf16 Bs[128 * 32];
    const int tid = threadIdx.x;
    const int lane = tid & 63;
    const int wave = tid >> 6;
    const int quad = lane >> 4, l16 = lane & 15;
    const long m0 = (long)blockIdx.y * 128;
    const long n0 = (long)blockIdx.x * 128;
    const int wm = (wave >> 1) * 64, wn = (wave & 1) * 64;
    const int s0 = tid, s1 = tid + 256;

    f32x4 acc[4][4] = {};

    for (int k0 = 0; k0 < K; k0 += 32) {
        gl_lds16(A + (m0 + (s0 >> 2)) * lda + k0 + (s0 & 3) * 8, As + s0 * 8);
        gl_lds16(A + (m0 + (s1 >> 2)) * lda + k0 + (s1 & 3) * 8, As + s1 * 8);
        gl_lds16(B + (n0 + (s0 >> 2)) * ldb + k0 + (s0 & 3) * 8, Bs + s0 * 8);
        gl_lds16(B + (n0 + (s1 >> 2)) * ldb + k0 + (s1 & 3) * 8, Bs + s1 * 8);
        __syncthreads();
        bf16x8 af[4], bfr[4];
#pragma unroll
        for (int i = 0; i < 4; ++i)
            af[i] = *(const bf16x8*)(As + (wm + i * 16 + l16) * 32 + quad * 8);
#pragma unroll
        for (int j = 0; j < 4; ++j)
            bfr[j] = *(const bf16x8*)(Bs + (wn + j * 16 + l16) * 32 + quad * 8);
#pragma unroll
        for (int i = 0; i < 4; ++i)
#pragma unroll
            for (int j = 0; j < 4; ++j)
                acc[i][j] = __builtin_amdgcn_mfma_f32_16x16x32_bf16(af[i], bfr[j], acc[i][j], 0, 0, 0);
        __syncthreads();
    }
#pragma unroll
    for (int i = 0; i < 4; ++i) {
        long row = m0 + wm + i * 16 + quad * 4;
#pragma unroll
        for (int j = 0; j < 4; ++j) {
            int col = (int)n0 + wn + j * 16 + l16;
            float bb = bias[col];
#pragma unroll
            for (int r = 0; r < 4; ++r) {
                float v = acc[i][j][r] + bb;
                if (BF16OUT)
                    ((__bf16*)C)[(row + r) * ldc + col] = (__bf16)v;
                else
                    ((float*)C)[(row + r) * ldc + col] = v;
            }
        }
    }
}

// ---------------------------------------------------------------------------
// transpose V slice of tqv into VT[bh][d][s]
// ---------------------------------------------------------------------------
__global__ __launch_bounds__(256) void transpose_v(
    const __bf16* __restrict__ TQV, __bf16* __restrict__ VT)
{
    __shared__ unsigned short tile[64 * 65];
    int bid = blockIdx.x;          // 1024 blocks
    int bh = bid >> 5, st = bid & 31;
    int b = bh >> 4, h = bh & 15;
    long srow = (long)b * 2048 + st * 64;
#pragma unroll
    for (int p = 0; p < 16; ++p) {
        int idx = p * 256 + threadIdx.x;
        int sl = idx >> 6, d = idx & 63;
        tile[sl * 65 + d] = ((const unsigned short*)TQV)[(srow + sl) * 2048 + 1024 + h * 64 + d];
    }
    __syncthreads();
#pragma unroll
    for (int p = 0; p < 16; ++p) {
        int idx = p * 256 + threadIdx.x;
        int d = idx >> 6, sl = idx & 63;
        ((unsigned short*)VT)[((long)bh * 64 + d) * 2048 + st * 64 + sl] = tile[sl * 65 + d];
    }
}

// ---------------------------------------------------------------------------
// Flash attention, transposed dataflow + causal pairing + dbuf K/V.
// grid (pair=16, bh=32); block = 4 waves; wave owns a 16-q strip per tile.
// S^T = K Q^T  (C cols = q -> per-lane softmax state, alpha lane-uniform).
// P^T packed to LDS as b64 writes; O^T = VT * P^T; vectorized epilogue.
// One barrier per kv iteration; K/V double-buffered, prefetch after barrier.
// ---------------------------------------------------------------------------
__global__ __launch_bounds__(256) void attn_kernel(
    const __bf16* __restrict__ Q,   // [4096][1024]
    const __bf16* __restrict__ Xb,  // [4096][1024]
    const __bf16* __restrict__ VT,  // [32*64][2048]
    __bf16* __restrict__ O)         // [4096][1024]
{
    __shared__ __bf16 Qs[2 * 4096];
    __shared__ __bf16 Ks[2 * 4096];
    __shared__ __bf16 Vs[2 * 4096];
    __shared__ __bf16 Ps[4 * 1024];
    const int tid = threadIdx.x;
    const int lane = tid & 63;
    const int wave = tid >> 6;
    const int quad = lane >> 4, l16 = lane & 15;
    const int qa = blockIdx.x;        // 0..15
    const int qb = 31 - qa;           // 16..31
    const int bh = blockIdx.y;
    const int b = bh >> 4, h = bh & 15;
    const long rowbase = (long)b * 2048;

    const int s0 = tid, s1 = tid + 256;
    const int c0 = ((s0 & 7) ^ ((s0 >> 3) & 7)) * 8;
    const int c1 = ((s1 & 7) ^ ((s1 >> 3) & 7)) * 8;

    // stage both Q tiles (swizzled source columns, linear LDS slots)
    gl_lds16(Q + (rowbase + qa * 64 + (s0 >> 3)) * 1024 + h * 64 + c0, Qs + s0 * 8);
    gl_lds16(Q + (rowbase + qa * 64 + (s1 >> 3)) * 1024 + h * 64 + c1, Qs + s1 * 8);
    gl_lds16(Q + (rowbase + qb * 64 + (s0 >> 3)) * 1024 + h * 64 + c0, Qs + 4096 + s0 * 8);
    gl_lds16(Q + (rowbase + qb * 64 + (s1 >> 3)) * 1024 + h * 64 + c1, Qs + 4096 + s1 * 8);

    auto stage_kv = [&](int j, int buf) {
        gl_lds16(Xb + (rowbase + j * 64 + (s0 >> 3)) * 1024 + h * 64 + c0, Ks + buf * 4096 + s0 * 8);
        gl_lds16(Xb + (rowbase + j * 64 + (s1 >> 3)) * 1024 + h * 64 + c1, Ks + buf * 4096 + s1 * 8);
        gl_lds16(VT + ((long)bh * 64 + (s0 >> 3)) * 2048 + j * 64 + c0, Vs + buf * 4096 + s0 * 8);
        gl_lds16(VT + ((long)bh * 64 + (s1 >> 3)) * 2048 + j * 64 + c1, Vs + buf * 4096 + s1 * 8);
    };
    stage_kv(0, 0);

    f32x4 oacc[2][4] = {};
    float m_run[2] = {-1e30f, -1e30f};
    float l_run[2] = {0.f, 0.f};
    __bf16* Pw = Ps + wave * 1024;

    for (int j = 0; j <= qb; ++j) {
        __syncthreads();                       // buf[j&1] ready; prev reads done
        if (j < qb) stage_kv(j + 1, (j + 1) & 1);
        const __bf16* Kb = Ks + (j & 1) * 4096;
        const __bf16* Vb = Vs + (j & 1) * 4096;

        // hoisted K and V fragments (shared by both q-tiles)
        bf16x8 kf[2][4], vf[2][4];
#pragma unroll
        for (int kk = 0; kk < 2; ++kk)
#pragma unroll
            for (int kt = 0; kt < 4; ++kt) {
                kf[kk][kt] = *swz(Kb, kt * 16 + l16, kk * 4 + quad);
                vf[kk][kt] = *swz(Vb, kt * 16 + l16, kk * 4 + quad);
            }

#pragma unroll
        for (int t = 0; t < 2; ++t) {
            if (t == 0 && j > qa) continue;
            const int qt = t ? qb : qa;

            // S^T = K Q^T : rows = kv, cols = q (this wave's 16-q strip)
            bf16x8 qf[2];
#pragma unroll
            for (int kk = 0; kk < 2; ++kk)
                qf[kk] = *swz(Qs + t * 4096, wave * 16 + l16, kk * 4 + quad);
            f32x4 sacc[4] = {};
#pragma unroll
            for (int kk = 0; kk < 2; ++kk)
#pragma unroll
                for (int kt = 0; kt < 4; ++kt)
                    sacc[kt] = __builtin_amdgcn_mfma_f32_16x16x32_bf16(
                        kf[kk][kt], qf[kk], sacc[kt], 0, 0, 0);

            // scale + mask (diagonal tile only)
            float sv[4][4];
            const bool diag = (j == qt);
            const int qloc = wave * 16 + l16;
#pragma unroll
            for (int kt = 0; kt < 4; ++kt)
#pragma unroll
                for (int r = 0; r < 4; ++r) {
                    float s = sacc[kt][r] * 0.125f;
                    if (diag && (kt * 16 + quad * 4 + r > qloc)) s = -1e30f;
                    sv[kt][r] = s;
                }

            // per-lane softmax (state for q = this lane's column)
            float mloc = -1e30f;
#pragma unroll
            for (int kt = 0; kt < 4; ++kt)
#pragma unroll
                for (int r = 0; r < 4; ++r) mloc = fmaxf(mloc, sv[kt][r]);
            mloc = fmaxf(mloc, __shfl_xor(mloc, 16));
            mloc = fmaxf(mloc, __shfl_xor(mloc, 32));
            float mnew = fmaxf(m_run[t], mloc);
            float alpha = __expf(m_run[t] - mnew);
            m_run[t] = mnew;

            float psum = 0.f;
#pragma unroll
            for (int kt = 0; kt < 4; ++kt) {
                bf16x4 pk;
#pragma unroll
                for (int r = 0; r < 4; ++r) {
                    float p = __expf(sv[kt][r] - mnew);
                    psum += p;
                    pk[r] = (__bf16)p;
                }
                // P^T[ q=l16 ][ kv = kt*16+quad*4 .. +4 ]  (swizzled b64 write)
                *(bf16x4*)((char*)Pw + l16 * 128 +
                           (((kt * 2 + (quad >> 1)) ^ (l16 & 7)) * 16) + (quad & 1) * 8) = pk;
            }
            l_run[t] = l_run[t] * alpha + psum;   // cross-quad sum deferred

#pragma unroll
            for (int dt = 0; dt < 4; ++dt)
#pragma unroll
                for (int r = 0; r < 4; ++r) oacc[t][dt][r] *= alpha;

            // O^T += VT * P^T   (per-wave P buffer; no barrier)
#pragma unroll
            for (int kk = 0; kk < 2; ++kk) {
                bf16x8 pf = *swz(Pw, l16, kk * 4 + quad);
#pragma unroll
                for (int dt = 0; dt < 4; ++dt)
                    oacc[t][dt] = __builtin_amdgcn_mfma_f32_16x16x32_bf16(
                        vf[kk][dt], pf, oacc[t][dt], 0, 0, 0);
            }
        }
    }

    // epilogue: finish l reduction across quads, normalize, vectorized store
#pragma unroll
    for (int t = 0; t < 2; ++t) {
        const int qt = t ? qb : qa;
        float lsum = l_run[t];
        lsum += __shfl_xor(lsum, 16);
        lsum += __shfl_xor(lsum, 32);
        float inv = 1.0f / lsum;
        long row = rowbase + qt * 64 + wave * 16 + l16;
#pragma unroll
        for (int dt = 0; dt < 4; ++dt) {
            bf16x4 ov;
#pragma unroll
            for (int r = 0; r < 4; ++r) ov[r] = (__bf16)(oacc[t][dt][r] * inv);
            *(bf16x4*)(O + row * 1024 + h * 64 + dt * 16 + quad * 4) = ov;
        }
    }
}

// ---------------------------------------------------------------------------
extern "C" void kernel_launch(void* const* d_in, const int* in_sizes, int n_in,
                              void* d_out, int out_size, void* d_ws, size_t ws_size,
                              hipStream_t stream) {
    const float* x   = (const float*)d_in[0];
    const float* caw = (const float*)d_in[1];
    const float* cab = (const float*)d_in[2];
    const float* cpw = (const float*)d_in[3];
    const float* cpb = (const float*)d_in[4];

    char* p = (char*)d_ws;
    auto alloc = [&](size_t bytes) {
        void* r = (void*)p;
        p += (bytes + 255) & ~(size_t)255;
        return r;
    };
    __bf16* xb   = (__bf16*)alloc(4096UL * 1024 * 2);   // x bf16
    __bf16* wqvt = (__bf16*)alloc(2048UL * 1024 * 2);   // [Wq;Wv]^T
    __bf16* wkn  = (__bf16*)alloc(1024UL * 1024 * 2);   // Wk rows
    __bf16* wpt  = (__bf16*)alloc(1024UL * 1024 * 2);   // Wp^T
    float*  bqv  = (float*) alloc(2048UL * 4);          // [qb;vb]
    __bf16* tqv  = (__bf16*)alloc(4096UL * 2048 * 2);   // [t | v]
    __bf16* qbuf = (__bf16*)alloc(4096UL * 1024 * 2);   // q
    __bf16* vt   = (__bf16*)alloc(2048UL * 2048 * 2);   // V^T per (b,h)
    __bf16* attn = (__bf16*)alloc(4096UL * 1024 * 2);   // attention out

    prep_kernel<<<8193, 256, 0, stream>>>(x, caw, cab, cpw, xb, wqvt, wkn, wpt, bqv);

    // tqv = x @ [Wq|Wv] + [qb|vb]
    gemm_bt<true><<<dim3(16, 32), 256, 0, stream>>>(xb, 1024, wqvt, 1024, bqv,
                                                    (void*)tqv, 2048, 1024);
    // VT from v half of tqv
    transpose_v<<<1024, 256, 0, stream>>>(tqv, vt);
    // q = t @ Wk^T + kb   (t = cols [0,1024) of tqv)
    gemm_bt<true><<<dim3(8, 32), 256, 0, stream>>>(tqv, 2048, wkn, 1024, cab + 1024,
                                                   (void*)qbuf, 1024, 1024);
    // attention (paired causal tiles, transposed dataflow)
    attn_kernel<<<dim3(16, 32), 256, 0, stream>>>(qbuf, xb, vt, attn);
    // out = attn @ Wp + pb (fp32)
    gemm_bt<false><<<dim3(8, 32), 256, 0, stream>>>(attn, 1024, wpt, 1024, cpb,
                                                    d_out, 1024, 1024);
    (void)in_sizes; (void)n_in; (void)out_size; (void)ws_size;
}